// Round 2
// baseline (695.310 us; speedup 1.0000x reference)
//
#include <hip/hip_runtime.h>

// IsoMaxPlusLossFirstPart: logits[b,k,h,w] = -|scale| * || xn(b,:,h,w) - pn(k,:) ||
// Round 2: remove LDS broadcast path entirely. A tiny pre-kernel L2-normalizes
// the 19x256 prototypes into d_ws laid out [c][20]; the main kernel reads them
// at wave-uniform addresses (-> s_load SMEM path, no VALU/LDS pipe cost, no
// lgkmcnt-vs-FMA serialization). Channel unroll 8 for 8 global_load_dwordx4 in
// flight per thread; nontemporal loads/stores for the zero-reuse streams.

typedef float f4 __attribute__((ext_vector_type(4)));

namespace {
constexpr int kC     = 256;
constexpr int kK     = 19;
constexpr int kKP    = 20;          // padded row: 80 B, 16B-aligned
constexpr int kHW    = 128 * 256;   // 32768
constexpr int kBlock = 256;
constexpr int kPix   = 4;           // pixels per thread (float4 along w)
constexpr int kUnroll= 8;           // channels per main-loop iter
}

// ---- pre-kernel: normalize prototypes into d_ws ----
// pn[c*20+k] = proto[k][c] / max(||proto[k]||, eps)   (transposed, padded)
// pp[k]      = sum(pn[k]^2)
__global__ void proto_norm_kernel(const float* __restrict__ proto,
                                  float* __restrict__ pn,
                                  float* __restrict__ pp)
{
    const int tid  = threadIdx.x;
    const int lane = tid & 63;
    const int wv   = tid >> 6;
    for (int k = wv; k < kK; k += 4) {
        float v[4];
        float ss = 0.f;
        #pragma unroll
        for (int j = 0; j < 4; ++j) {
            v[j] = proto[k * kC + j * 64 + lane];
            ss = fmaf(v[j], v[j], ss);
        }
        #pragma unroll
        for (int m = 1; m < 64; m <<= 1)
            ss += __shfl_xor(ss, m, 64);
        const float inv = 1.0f / fmaxf(sqrtf(ss), 1e-12f);
        #pragma unroll
        for (int j = 0; j < 4; ++j)
            pn[(j * 64 + lane) * kKP + k] = v[j] * inv;
        if (lane == 0) pp[k] = ss * inv * inv;
    }
    // zero the pad column so the 5th quad never carries poison
    if (tid < kC) pn[tid * kKP + kK] = 0.f;
}

// ---- main kernel ----
__global__ __launch_bounds__(kBlock, 2)
void isomax_main(const float* __restrict__ feat,
                 const float* __restrict__ pn,
                 const float* __restrict__ pp,
                 const float* __restrict__ dscale,
                 float* __restrict__ out)
{
    const int tid  = threadIdx.x;
    const int gpix = (blockIdx.x * kBlock + tid) * kPix;
    const int b    = gpix >> 15;          // / kHW
    const int hw   = gpix & (kHW - 1);    // % kHW
    const float* fp = feat + (size_t)b * kC * kHW + hw;

    float xx[4] = {0.f, 0.f, 0.f, 0.f};
    f4 dot[kK];
    #pragma unroll
    for (int k = 0; k < kK; ++k) dot[k] = (f4)(0.f);

    for (int cc = 0; cc < kC; cc += kUnroll) {
        f4 v[kUnroll];
        #pragma unroll
        for (int u = 0; u < kUnroll; ++u)   // 8 x 16B loads in flight
            v[u] = __builtin_nontemporal_load(
                       (const f4*)(fp + (size_t)(cc + u) * kHW));
        #pragma unroll
        for (int u = 0; u < kUnroll; ++u) {
            const int c = cc + u;
            // wave-uniform address -> s_load (SMEM), operand folds as SGPR
            const f4* __restrict__ prow = (const f4*)(pn + (size_t)c * kKP);
            f4 P[5];
            #pragma unroll
            for (int q = 0; q < 5; ++q) P[q] = prow[q];
            const float* p = (const float*)P;
            xx[0] = fmaf(v[u].x, v[u].x, xx[0]);
            xx[1] = fmaf(v[u].y, v[u].y, xx[1]);
            xx[2] = fmaf(v[u].z, v[u].z, xx[2]);
            xx[3] = fmaf(v[u].w, v[u].w, xx[3]);
            #pragma unroll
            for (int k = 0; k < kK; ++k) {
                dot[k].x = fmaf(p[k], v[u].x, dot[k].x);
                dot[k].y = fmaf(p[k], v[u].y, dot[k].y);
                dot[k].z = fmaf(p[k], v[u].z, dot[k].z);
                dot[k].w = fmaf(p[k], v[u].w, dot[k].w);
            }
        }
    }

    float inv[4], xnsq[4];
    #pragma unroll
    for (int j = 0; j < 4; ++j) {
        inv[j]  = 1.0f / fmaxf(sqrtf(xx[j]), 1e-12f);
        xnsq[j] = xx[j] * inv[j] * inv[j];
    }
    const float sc = fabsf(dscale[0]);

    float* op = out + (size_t)b * kK * kHW + hw;
    #pragma unroll
    for (int k = 0; k < kK; ++k) {
        const float ppk = pp[k];            // uniform -> s_load
        f4 o;
        o.x = -sc * sqrtf(fmaxf(xnsq[0] + ppk - 2.0f * dot[k].x * inv[0], 0.f));
        o.y = -sc * sqrtf(fmaxf(xnsq[1] + ppk - 2.0f * dot[k].y * inv[1], 0.f));
        o.z = -sc * sqrtf(fmaxf(xnsq[2] + ppk - 2.0f * dot[k].z * inv[2], 0.f));
        o.w = -sc * sqrtf(fmaxf(xnsq[3] + ppk - 2.0f * dot[k].w * inv[3], 0.f));
        __builtin_nontemporal_store(o, (f4*)(op + (size_t)k * kHW));
    }
}

extern "C" void kernel_launch(void* const* d_in, const int* in_sizes, int n_in,
                              void* d_out, int out_size, void* d_ws, size_t ws_size,
                              hipStream_t stream) {
    const float* feat   = (const float*)d_in[0];
    const float* proto  = (const float*)d_in[1];
    const float* dscale = (const float*)d_in[2];
    float* out = (float*)d_out;

    float* pn = (float*)d_ws;               // [256][20]
    float* pp = pn + kC * kKP;              // [19]

    proto_norm_kernel<<<dim3(1), dim3(256), 0, stream>>>(proto, pn, pp);

    const int npix    = in_sizes[0] / kC;   // 524288
    const int threads = npix / kPix;        // 131072
    isomax_main<<<dim3(threads / kBlock), dim3(kBlock), 0, stream>>>(
        feat, pn, pp, dscale, out);
}